// Round 14
// baseline (281.341 us; speedup 1.0000x reference)
//
#include <hip/hip_runtime.h>
#include <math.h>

#define SB 64
#define SS 512
#define SH 768
#define NT 36
#define TSTART 34
#define TSTOP 35
#define NC 32
#define CL 16

#define CFENCE() asm volatile("" ::: "memory")

__device__ __forceinline__ float wave_max_f(float v) {
#pragma unroll
    for (int off = 32; off > 0; off >>= 1) v = fmaxf(v, __shfl_xor(v, off, 64));
    return v;
}
__device__ __forceinline__ float wave_sum_f(float v) {
#pragma unroll
    for (int off = 32; off > 0; off >>= 1) v += __shfl_xor(v, off, 64);
    return v;
}
__device__ __forceinline__ float bcast0(float v) {
    return __uint_as_float(__builtin_amdgcn_readfirstlane(__float_as_uint(v)));
}

// ---------------- emissions ----------------
// emit[32768][36] = leaky_relu(Xg[32768][768] @ W[768][36] + b)
// Coalesced-X LDS staging (R12) + W VIA VECTOR PATH (new):
// R13's _ord-75 dispatch proved emit time is invariant to X in L3 vs HBM
// (65us either way) -> not X-bound, not FMA-bound (VALU 23%). The
// serialized resource was the SCALAR pipe: wave-uniform s_load of W
// (3456 floats/wave through ~100 SGPRs, lgkm-gated ~16-dword batches,
// sL1 thrashed by 16 waves x different W chunks -> MLP ~2-4).
// Fix: W address forced into a VGPR (opaque v_mov) -> 9 x
// global_load_dwordx4 per k-row, lane-uniform (coalesced to one L1 line
// broadcast), deep vmcnt MLP, L1/L2-hot. 864 loads/wave hide under
// 6912 FMA cycles.
#define XP 129
#define XBUF 8256
#define RED(qq, rr, jj) smem[(qq) * 2368 + (rr) * 37 + (jj)]

#define WFMA(i, wv)                                                      \
    acc[4*(i)+0] += xv * (wv).x; acc[4*(i)+1] += xv * (wv).y;            \
    acc[4*(i)+2] += xv * (wv).z; acc[4*(i)+3] += xv * (wv).w;

extern "C" __global__ __launch_bounds__(512) void k_emit(
    const float* __restrict__ x1, const int* __restrict__ hidx,
    const float* __restrict__ W, const float* __restrict__ bias,
    float* __restrict__ emit)
{
    __shared__ __align__(16) float smem[18944];   // 75,776 B: xbuf[2][64][129] / red[8][64][37]

    int tid  = threadIdx.x;
    int lane = tid & 63;
    int q    = __builtin_amdgcn_readfirstlane(tid >> 6);   // scalar: LDS/red indexing

    // opaque VGPR copy of q: defeats uniformity analysis so W loads take
    // the VECTOR memory path (global_load_dwordx4), not scalar s_load
    int qv;
    asm("v_mov_b32 %0, %1" : "=v"(qv) : "v"(tid >> 6));

    int srow = tid >> 3;
    int c8   = tid & 7;
    int grs  = blockIdx.x * 64 + srow;
    int bs   = grs >> 9;
    const float4* srcRow = (const float4*)(x1 + (size_t)(bs * SS + hidx[grs]) * SH);
    int woff = srow * XP + c8 * 4;

    float acc[NT];
#pragma unroll
    for (int j = 0; j < NT; ++j) acc[j] = 0.f;

    float4 n0, n1, n2, n3;
    n0 = srcRow[c8];  n1 = srcRow[c8 + 8];
    n2 = srcRow[c8 + 16]; n3 = srcRow[c8 + 24];
    {
        float* d = smem + woff;
        d[0] = n0.x; d[1] = n0.y; d[2] = n0.z; d[3] = n0.w;
        d[32] = n1.x; d[33] = n1.y; d[34] = n1.z; d[35] = n1.w;
        d[64] = n2.x; d[65] = n2.y; d[66] = n2.z; d[67] = n2.w;
        d[96] = n3.x; d[97] = n3.y; d[98] = n3.z; d[99] = n3.w;
    }

#pragma unroll
    for (int s = 0; s < 6; ++s) {
        if (s < 5) {
            int f0 = (s + 1) * 32 + c8;
            n0 = srcRow[f0]; n1 = srcRow[f0 + 8];
            n2 = srcRow[f0 + 16]; n3 = srcRow[f0 + 24];
        }
        __syncthreads();
        {
            const float* xs = smem + (s & 1) * XBUF + lane * XP + 16 * q;
            const float4* Wv = (const float4*)W + (size_t)(128 * s + 16 * qv) * 9;
#pragma unroll
            for (int k = 0; k < 16; ++k) {
                float xv = xs[k];
                const float4* wk = Wv + k * 9;
                float4 w0 = wk[0], w1 = wk[1], w2 = wk[2];
                WFMA(0, w0) WFMA(1, w1) WFMA(2, w2)
                float4 w3 = wk[3], w4 = wk[4], w5 = wk[5];
                WFMA(3, w3) WFMA(4, w4) WFMA(5, w5)
                float4 w6 = wk[6], w7 = wk[7], w8 = wk[8];
                WFMA(6, w6) WFMA(7, w7) WFMA(8, w8)
            }
        }
        if (s < 5) {
            float* d = smem + ((s + 1) & 1) * XBUF + woff;
            d[0] = n0.x; d[1] = n0.y; d[2] = n0.z; d[3] = n0.w;
            d[32] = n1.x; d[33] = n1.y; d[34] = n1.z; d[35] = n1.w;
            d[64] = n2.x; d[65] = n2.y; d[66] = n2.z; d[67] = n2.w;
            d[96] = n3.x; d[97] = n3.y; d[98] = n3.z; d[99] = n3.w;
        }
    }
    __syncthreads();

#pragma unroll
    for (int j = 0; j < NT; ++j) RED(q, lane, j) = acc[j];
    __syncthreads();

    int r = tid >> 2, g = tid & 3;
    float vout[9];
    if (tid < 256) {
#pragma unroll
        for (int jj = 0; jj < 9; ++jj) {
            int j = g * 9 + jj;
            float v = bias[j];
#pragma unroll
            for (int qq = 0; qq < 8; ++qq) v += RED(qq, r, j);
            vout[jj] = v > 0.f ? v : 0.01f * v;
        }
    }
    __syncthreads();
    if (tid < 256) {
#pragma unroll
        for (int jj = 0; jj < 9; ++jj) smem[r * NT + g * 9 + jj] = vout[jj];
    }
    __syncthreads();
    {
        const float4* st4 = (const float4*)smem;
        float4* op = (float4*)(emit + (size_t)blockIdx.x * 64 * NT);
        for (int i = tid; i < 576; i += 512) op[i] = st4[i];
    }
}

// ---------------- fused scan, merged kinds (R13-verified) ----------------
#define STEP2(T, WRITEBP)                                                 \
    {                                                                     \
        float e_t = elsw[((T) - t0s) * NT + jj];                          \
        float mL = bcast0(aL);                                            \
        bcL[lane] = __expf(aL - mL);                                      \
        bcV[lane] = aV;                                                   \
        CFENCE();                                                         \
        __builtin_amdgcn_wave_barrier();                                  \
        float s0 = 0.f, s1 = 0.f, s2 = 0.f, s3 = 0.f;                     \
        float b0 = -1e30f, b1 = -1e30f, b2 = -1e30f, b3 = -1e30f;         \
        int   i0 = 0, i1 = 1, i2 = 2, i3 = 3;                             \
        _Pragma("unroll")                                                 \
        for (int k = 0; k < 9; ++k) {                                     \
            float4 pv = bcL4[w][k];                                       \
            float4 dv = bcV4[w][k];                                       \
            s0 += pv.x * Ecol[4 * k];                                     \
            s1 += pv.y * Ecol[4 * k + 1];                                 \
            s2 += pv.z * Ecol[4 * k + 2];                                 \
            s3 += pv.w * Ecol[4 * k + 3];                                 \
            float c0 = dv.x + tcol[4 * k];                                \
            float c1 = dv.y + tcol[4 * k + 1];                            \
            float c2 = dv.z + tcol[4 * k + 2];                            \
            float c3 = dv.w + tcol[4 * k + 3];                            \
            if (c0 > b0) { b0 = c0; i0 = 4 * k; }                         \
            if (c1 > b1) { b1 = c1; i1 = 4 * k + 1; }                     \
            if (c2 > b2) { b2 = c2; i2 = 4 * k + 2; }                     \
            if (c3 > b3) { b3 = c3; i3 = 4 * k + 3; }                     \
        }                                                                 \
        CFENCE();                                                         \
        float anewL = mL + __logf((s0 + s1) + (s2 + s3)) + e_t;           \
        float best = b0; int bi = i0;                                     \
        if (b1 > best || (b1 == best && i1 < bi)) { best = b1; bi = i1; } \
        if (b2 > best || (b2 == best && i2 < bi)) { best = b2; bi = i2; } \
        if (b3 > best || (b3 == best && i3 < bi)) { best = b3; bi = i3; } \
        aL = act ? anewL : -1e30f;                                        \
        aV = act ? (best + e_t) : -1e30f;                                 \
        if ((WRITEBP) && act)                                             \
            bp[((size_t)b * SS + (T)) * 64 + jj] = (unsigned char)bi;     \
    }

extern "C" __global__ __launch_bounds__(256) void k_scan(
    const float* __restrict__ emit, const int* __restrict__ hidx,
    const float* __restrict__ trans,
    float* __restrict__ Warr, float* __restrict__ Earr,
    float* __restrict__ lse_local,
    float* __restrict__ score_local, int* __restrict__ ltag,
    unsigned char* __restrict__ bp)
{
    __shared__ float trl[NT * NT];
    __shared__ float els[4][1024];
    __shared__ float4 bcL4[4][16];
    __shared__ float4 bcV4[4][16];

    int tid  = threadIdx.x;
    int lane = tid & 63;
    int w    = __builtin_amdgcn_readfirstlane(tid >> 6);

    int wid  = blockIdx.x * 4 + w;   // 0..2047
    int b    = wid >> 5;
    int c    = wid & 31;

    const float* eb  = emit + (size_t)b * SS * NT;
    int t0s = (c > 0) ? (c * CL - 9) : 0;
    const float* ebase = eb + (size_t)t0s * NT;
    float* elsw = els[w];

#pragma unroll
    for (int i = 0; i < 4; ++i) {
        __builtin_amdgcn_global_load_lds(
            (const __attribute__((address_space(1))) void*)(ebase + i * 256 + lane * 4),
            (__attribute__((address_space(3))) void*)(elsw + i * 256), 16, 0, 0);
    }
    for (int i = tid; i < NT * NT; i += 256) trl[i] = trans[i];

    int  jj  = lane < NT ? lane : NT - 1;
    bool act = lane < NT;

    int xm = 0;
    const int* hb = hidx + b * SS;
#pragma unroll
    for (int k = 0; k < SS / 64; ++k) xm = max(xm, hb[lane + 64 * k]);
#pragma unroll
    for (int off = 32; off > 0; off >>= 1) xm = max(xm, __shfl_xor(xm, off, 64));
    int xlen = xm;
    int cl   = (xlen >= 1) ? ((xlen - 1) >> 4) : 0;

    int tb0 = c * CL - 8;
    int te0 = c * CL; if (te0 > xlen) te0 = xlen; te0 -= 1;
    int tb  = c * CL; if (tb < 1) tb = 1;
    int te  = (c + 1) * CL; if (te > xlen) te = xlen; te -= 1;

    float init;
    if (c == 0) init = act ? (eb[jj] + trans[TSTART * NT + jj]) : -1e30f;
    else        init = act ? eb[(size_t)(tb0 - 1) * NT + jj] : -1e30f;
    float aL = init, aV = init;

    __syncthreads();

    float* bcL = (float*)bcL4[w];
    float* bcV = (float*)bcV4[w];

    float tcol[NT], Ecol[NT];
#pragma unroll
    for (int i = 0; i < NT; ++i) {
        tcol[i] = trl[i * NT + jj];
        Ecol[i] = __expf(tcol[i]);
    }

    if (c > 0) {
        for (int t = tb0; t <= te0; ++t) STEP2(t, 0)
    }
    float WvL = bcast0(aL), WvV = bcast0(aV);
    for (int t = tb; t <= te; ++t) STEP2(t, 1)
    float EvL = bcast0(aL), EvV = bcast0(aV);

    if (lane == 0) {
        Warr[b * NC + c]        = WvL;
        Earr[b * NC + c]        = EvL;
        Warr[(SB + b) * NC + c] = WvV;
        Earr[(SB + b) * NC + c] = EvV;
    }

    if (c == cl) {
        float ffL = act ? (aL + trl[jj * NT + TSTOP]) : -1e30f;
        float M = wave_max_f(ffL);
        float ssum = wave_sum_f(__expf(ffL - M));
        if (lane == 0) lse_local[b] = M + __logf(ssum);

        float ffV = act ? (aV + trl[jj * NT + TSTOP]) : -1e30f;
        float bv = ffV; int bi = lane;
#pragma unroll
        for (int off = 32; off > 0; off >>= 1) {
            float ov = __shfl_xor(bv, off, 64);
            int   oi = __shfl_xor(bi, off, 64);
            if (ov > bv || (ov == bv && oi < bi)) { bv = ov; bi = oi; }
        }
        if (lane == 0) { score_local[b] = bv; ltag[b] = bi; }
    }
}

// ---------------- finalize: parallel backtrace + loss atomicAdd ----------------
extern "C" __global__ __launch_bounds__(1024) void k_final(
    const float* __restrict__ emit, const int* __restrict__ hidx,
    const int* __restrict__ tags, const float* __restrict__ trans,
    const float* __restrict__ Warr, const float* __restrict__ Earr,
    const float* __restrict__ lse_local,
    const float* __restrict__ score_local, const int* __restrict__ ltag,
    const unsigned char* __restrict__ bp,
    float* __restrict__ loss_out, float* __restrict__ path_out,
    float* __restrict__ score_out)
{
    __shared__ unsigned char bpl[SS * 64];
    __shared__ unsigned char cmap[SS][40];
    __shared__ unsigned char exitmap[NC][64];
    __shared__ float gred[16];
    __shared__ int   ent[NC];

    int tid  = threadIdx.x;
    int lane = tid & 63;
    int w    = tid >> 6;
    int b    = blockIdx.x;

    {
        const int4* src = (const int4*)(bp + (size_t)b * SS * 64);
        int4* dst = (int4*)bpl;
        for (int i = tid; i < SS * 4; i += 1024) dst[i] = src[i];
    }

    int xm = 0;
    const int* hb = hidx + b * SS;
#pragma unroll
    for (int k = 0; k < SS / 64; ++k) xm = max(xm, hb[lane + 64 * k]);
#pragma unroll
    for (int off = 32; off > 0; off >>= 1) xm = max(xm, __shfl_xor(xm, off, 64));
    int xlen = xm;
    int cl   = (xlen >= 1) ? ((xlen - 1) >> 4) : 0;

    float g = 0.f;
    const int* tg = tags + b * SS;
    if (tid < SS) {
        int t = tid;
        if (t < xlen) {
            int tt = tg[t];
            g += emit[((size_t)b * SS + t) * NT + tt];
            if (t >= 1) g += trans[tg[t - 1] * NT + tt];
        }
    }
    g = wave_sum_f(g);
    if (lane == 0) gred[w] = g;

    float kf = 0.f, kv = 0.f;
    if (w == 8) {
        if (lane < cl) {
            kf = Earr[(0 * SB + b) * NC + lane] - Warr[(0 * SB + b) * NC + lane + 1];
            kv = Earr[(1 * SB + b) * NC + lane] - Warr[(1 * SB + b) * NC + lane + 1];
        }
        kf = wave_sum_f(kf);
        kv = wave_sum_f(kv);
    }

    __syncthreads();

    if (tid == 512) {
        float gold = 0.f;
#pragma unroll
        for (int i = 0; i < 8; ++i) gold += gred[i];
        int tg0 = tg[0];
        int lt  = (xlen >= 1) ? tg[xlen - 1] : tg0;
        gold += trans[TSTART * NT + tg0] + trans[lt * NT + TSTOP];
        atomicAdd(loss_out, (lse_local[b] + kf) - gold);
        score_out[b] = score_local[b] + kv;
    }

    for (int cc = 0; cc < 2; ++cc) {
        int c = w * 2 + cc;
        if (xlen >= 1 && c <= cl) {
            int tb = (c == 0) ? 1 : c * CL;
            int te = c * CL + CL - 1; if (te > xlen - 1) te = xlen - 1;
            int m = lane;
            if (lane < NT) cmap[te][lane] = (unsigned char)m;
            for (int t = te; t >= tb; --t) {
                m = bpl[t * 64 + m];
                if (lane < NT) {
                    if (t > tb || c == 0) cmap[t - 1][lane] = (unsigned char)m;
                    else                  exitmap[c][lane]  = (unsigned char)m;
                }
            }
        }
    }
    __syncthreads();

    if (tid == 0 && xlen >= 1) {
        int e = ltag[b];
        for (int c2 = cl; c2 >= 0; --c2) {
            ent[c2] = e;
            if (c2 > 0) e = exitmap[c2][e];
        }
    }
    __syncthreads();

    if (tid < SS) {
        int t = tid;
        float* op = path_out + (size_t)b * SS;
        if (t >= xlen) op[t] = 0.f;
        else           op[t] = (float)cmap[t][ent[t >> 4]];
    }
}

extern "C" void kernel_launch(void* const* d_in, const int* in_sizes, int n_in,
                              void* d_out, int out_size, void* d_ws, size_t ws_size,
                              hipStream_t stream)
{
    const float* x1    = (const float*)d_in[0];
    const int*   hidx  = (const int*)d_in[1];
    const int*   tags  = (const int*)d_in[2];
    const float* W     = (const float*)d_in[3];
    const float* bias  = (const float*)d_in[4];
    const float* trans = (const float*)d_in[5];
    float* out = (float*)d_out;

    float* emit        = (float*)d_ws;
    float* Warr        = emit + (size_t)SB * SS * NT;
    float* Earr        = Warr + 2 * SB * NC;
    float* lse_local   = Earr + 2 * SB * NC;
    float* score_local = lse_local + SB;
    int*   ltag        = (int*)(score_local + SB);
    float* spacer      = (float*)(ltag + SB);
    unsigned char* bp  = (unsigned char*)(spacer + SB);

    hipLaunchKernelGGL(k_emit, dim3(SB * SS / 64), dim3(512), 0, stream,
                       x1, hidx, W, bias, emit);
    hipLaunchKernelGGL(k_scan, dim3(512), dim3(256), 0, stream,
                       emit, hidx, trans, Warr, Earr, lse_local,
                       score_local, ltag, bp);
    hipLaunchKernelGGL(k_final, dim3(SB), dim3(1024), 0, stream,
                       emit, hidx, tags, trans, Warr, Earr, lse_local,
                       score_local, ltag, bp, out, out + 1, out + 1 + SB * SS);
}

// Round 15
// 260.009 us; speedup vs baseline: 1.0820x; 1.0820x over previous
//
#include <hip/hip_runtime.h>
#include <math.h>

#define SB 64
#define SS 512
#define SH 768
#define NT 36
#define TSTART 34
#define TSTOP 35
#define NC 32
#define CL 16

#define CFENCE() asm volatile("" ::: "memory")

__device__ __forceinline__ float wave_max_f(float v) {
#pragma unroll
    for (int off = 32; off > 0; off >>= 1) v = fmaxf(v, __shfl_xor(v, off, 64));
    return v;
}
__device__ __forceinline__ float wave_sum_f(float v) {
#pragma unroll
    for (int off = 32; off > 0; off >>= 1) v += __shfl_xor(v, off, 64);
    return v;
}
__device__ __forceinline__ float bcast0(float v) {
    return __uint_as_float(__builtin_amdgcn_readfirstlane(__float_as_uint(v)));
}

// ---------------- emissions: K-split partials at 32 waves/CU ----------------
// emitA/emitB[32768][36] = Xg[.][384kb..+384) @ W-half (RAW partial, no bias).
// Occupancy ladder measured: 8 w/CU -> 70us, 16 w/CU -> 63-67us (all variants).
// This version: grid 1024 (512 row-blocks x 2 K-halves), LDS 37.9KB
// (red[4] pairwise slabs; xbuf[2][64][65]=33.3KB aliased in same smem)
// -> 4 blocks/CU = 32 waves/CU. launch_bounds(512,8) pins VGPR<=64
// (safe: ~54 live regs; R6's failure needed 110). s_load W (vector-W
// broadcast measured 2x WORSE in R14). bias+leaky fold into consumers.
#define XP 65
#define XBUFF 4160                       // 64*65 floats per buffer
#define RED(p, r, j) smem[(p) * 2368 + (r) * 37 + (j)]

extern "C" __global__ __launch_bounds__(512, 8) void k_emit(
    const float* __restrict__ x1, const int* __restrict__ hidx,
    const float* __restrict__ W, const float* __restrict__ bias,
    float* __restrict__ emitA, float* __restrict__ emitB)
{
    __shared__ __align__(16) float smem[9472];   // 37,888 B

    int tid  = threadIdx.x;
    int lane = tid & 63;
    int q    = __builtin_amdgcn_readfirstlane(tid >> 6);   // 0..7
    int kb   = blockIdx.x & 1;                             // K-half
    int rb   = blockIdx.x >> 1;                            // row-block

    int srow = tid >> 3;          // 0..63
    int c8   = tid & 7;           // 0..7
    int grs  = rb * 64 + srow;
    int bs   = grs >> 9;
    const float4* srcRow = (const float4*)(x1 + (size_t)(bs * SS + hidx[grs]) * SH) + kb * 96;
    int woff = srow * XP + c8 * 8;

    float acc[NT];
#pragma unroll
    for (int j = 0; j < NT; ++j) acc[j] = 0.f;

    // prologue: stage slice 0 into buf 0 (16 float4/row; thread: 2 float4)
    float4 n0 = srcRow[2 * c8], n1 = srcRow[2 * c8 + 1];
    {
        float* d = smem + woff;
        d[0] = n0.x; d[1] = n0.y; d[2] = n0.z; d[3] = n0.w;
        d[4] = n1.x; d[5] = n1.y; d[6] = n1.z; d[7] = n1.w;
    }

#pragma unroll
    for (int s = 0; s < 6; ++s) {
        if (s < 5) {
            int f0 = (s + 1) * 16 + 2 * c8;
            n0 = srcRow[f0]; n1 = srcRow[f0 + 1];
        }
        __syncthreads();
        {
            const float* xs = smem + (s & 1) * XBUFF + lane * XP + 8 * q;
            const float* Ws = W + (size_t)(kb * 384 + 64 * s + 8 * q) * NT;   // wave-uniform -> s_load
#pragma unroll
            for (int k = 0; k < 8; ++k) {
                float xv = xs[k];
                const float* wr = Ws + k * NT;
#pragma unroll
                for (int j = 0; j < NT; ++j) acc[j] += xv * wr[j];
            }
        }
        if (s < 5) {
            float* d = smem + ((s + 1) & 1) * XBUFF + woff;
            d[0] = n0.x; d[1] = n0.y; d[2] = n0.z; d[3] = n0.w;
            d[4] = n1.x; d[5] = n1.y; d[6] = n1.z; d[7] = n1.w;
        }
    }
    __syncthreads();   // xbuf reads done -> red slabs may alias

    // pairwise reduce 8 -> 4 -> 2 -> 1 (R4-verified network)
    if (q >= 4) {
#pragma unroll
        for (int j = 0; j < NT; ++j) RED(q - 4, lane, j) = acc[j];
    }
    __syncthreads();
    if (q < 4) {
#pragma unroll
        for (int j = 0; j < NT; ++j) acc[j] += RED(q, lane, j);
    }
    __syncthreads();
    if (q == 2 || q == 3) {
#pragma unroll
        for (int j = 0; j < NT; ++j) RED(q - 2, lane, j) = acc[j];
    }
    __syncthreads();
    if (q < 2) {
#pragma unroll
        for (int j = 0; j < NT; ++j) acc[j] += RED(q, lane, j);
    }
    __syncthreads();
    if (q == 1) {
#pragma unroll
        for (int j = 0; j < NT; ++j) RED(1, lane, j) = acc[j];
    }
    __syncthreads();
    if (q == 0) {
        alignas(16) float vout[NT];
#pragma unroll
        for (int j = 0; j < NT; ++j) vout[j] = acc[j] + RED(1, lane, j);   // RAW partial
        float* outp = kb ? emitB : emitA;
        float4* op = (float4*)(outp + (size_t)(rb * 64 + lane) * NT);
        const float4* vv = (const float4*)vout;
#pragma unroll
        for (int i = 0; i < 9; ++i) op[i] = vv[i];
    }
}

// ---------------- fused scan, merged kinds; consumes A+B+bias+leaky ---------
#define STEP2(T, WRITEBP)                                                 \
    {                                                                     \
        float e_t = elsw[((T) - t0s) * NT + jj];                          \
        float mL = bcast0(aL);                                            \
        bcL[lane] = __expf(aL - mL);                                      \
        bcV[lane] = aV;                                                   \
        CFENCE();                                                         \
        __builtin_amdgcn_wave_barrier();                                  \
        float s0 = 0.f, s1 = 0.f, s2 = 0.f, s3 = 0.f;                     \
        float b0 = -1e30f, b1 = -1e30f, b2 = -1e30f, b3 = -1e30f;         \
        int   i0 = 0, i1 = 1, i2 = 2, i3 = 3;                             \
        _Pragma("unroll")                                                 \
        for (int k = 0; k < 9; ++k) {                                     \
            float4 pv = bcL4[w][k];                                       \
            float4 dv = bcV4[w][k];                                       \
            s0 += pv.x * Ecol[4 * k];                                     \
            s1 += pv.y * Ecol[4 * k + 1];                                 \
            s2 += pv.z * Ecol[4 * k + 2];                                 \
            s3 += pv.w * Ecol[4 * k + 3];                                 \
            float c0 = dv.x + tcol[4 * k];                                \
            float c1 = dv.y + tcol[4 * k + 1];                            \
            float c2 = dv.z + tcol[4 * k + 2];                            \
            float c3 = dv.w + tcol[4 * k + 3];                            \
            if (c0 > b0) { b0 = c0; i0 = 4 * k; }                         \
            if (c1 > b1) { b1 = c1; i1 = 4 * k + 1; }                     \
            if (c2 > b2) { b2 = c2; i2 = 4 * k + 2; }                     \
            if (c3 > b3) { b3 = c3; i3 = 4 * k + 3; }                     \
        }                                                                 \
        CFENCE();                                                         \
        float anewL = mL + __logf((s0 + s1) + (s2 + s3)) + e_t;           \
        float best = b0; int bi = i0;                                     \
        if (b1 > best || (b1 == best && i1 < bi)) { best = b1; bi = i1; } \
        if (b2 > best || (b2 == best && i2 < bi)) { best = b2; bi = i2; } \
        if (b3 > best || (b3 == best && i3 < bi)) { best = b3; bi = i3; } \
        aL = act ? anewL : -1e30f;                                        \
        aV = act ? (best + e_t) : -1e30f;                                 \
        if ((WRITEBP) && act)                                             \
            bp[((size_t)b * SS + (T)) * 64 + jj] = (unsigned char)bi;     \
    }

extern "C" __global__ __launch_bounds__(256) void k_scan(
    const float* __restrict__ emA, const float* __restrict__ emB,
    const float* __restrict__ bias,
    const int* __restrict__ hidx, const float* __restrict__ trans,
    float* __restrict__ Warr, float* __restrict__ Earr,
    float* __restrict__ lse_local,
    float* __restrict__ score_local, int* __restrict__ ltag,
    unsigned char* __restrict__ bp)
{
    __shared__ float trl[NT * NT];
    __shared__ float bbl[40];
    __shared__ __align__(16) float els[4][1024];
    __shared__ float4 bcL4[4][16];
    __shared__ float4 bcV4[4][16];

    int tid  = threadIdx.x;
    int lane = tid & 63;
    int w    = __builtin_amdgcn_readfirstlane(tid >> 6);

    int wid  = blockIdx.x * 4 + w;   // 0..2047
    int b    = wid >> 5;
    int c    = wid & 31;

    size_t eboff = (size_t)b * SS * NT;
    int t0s = (c > 0) ? (c * CL - 9) : 0;
    size_t wbase = eboff + (size_t)t0s * NT;   // 16B-aligned (144B rows)
    float* elsw = els[w];

    for (int i = tid; i < NT * NT; i += 256) trl[i] = trans[i];
    if (tid < NT) bbl[tid] = bias[tid];

    int  jj  = lane < NT ? lane : NT - 1;
    bool act = lane < NT;

    int xm = 0;
    const int* hb = hidx + b * SS;
#pragma unroll
    for (int k = 0; k < SS / 64; ++k) xm = max(xm, hb[lane + 64 * k]);
#pragma unroll
    for (int off = 32; off > 0; off >>= 1) xm = max(xm, __shfl_xor(xm, off, 64));
    int xlen = xm;
    int cl   = (xlen >= 1) ? ((xlen - 1) >> 4) : 0;

    int tb0 = c * CL - 8;
    int te0 = c * CL; if (te0 > xlen) te0 = xlen; te0 -= 1;
    int tb  = c * CL; if (tb < 1) tb = 1;
    int te  = (c + 1) * CL; if (te > xlen) te = xlen; te -= 1;

    __syncthreads();   // trl + bbl visible

    // combine A+B + bias + leaky into the per-wave els window (wave-local)
    {
        const float4* A4 = (const float4*)(emA + wbase);
        const float4* B4 = (const float4*)(emB + wbase);
        float4* E4 = (float4*)elsw;
        for (int i4 = lane; i4 < 256; i4 += 64) {
            float4 a = A4[i4], bb = B4[i4];
            int f0 = i4 * 4;
            int j0 = f0 % 36;
            int j1 = (j0 + 1 == 36) ? 0 : j0 + 1;
            int j2 = (j1 + 1 == 36) ? 0 : j1 + 1;
            int j3 = (j2 + 1 == 36) ? 0 : j2 + 1;
            float4 v;
            v.x = a.x + bb.x + bbl[j0]; v.x = v.x > 0.f ? v.x : 0.01f * v.x;
            v.y = a.y + bb.y + bbl[j1]; v.y = v.y > 0.f ? v.y : 0.01f * v.y;
            v.z = a.z + bb.z + bbl[j2]; v.z = v.z > 0.f ? v.z : 0.01f * v.z;
            v.w = a.w + bb.w + bbl[j3]; v.w = v.w > 0.f ? v.w : 0.01f * v.w;
            E4[i4] = v;
        }
    }

    float init;
    if (c == 0) {
        float ev = emA[eboff + jj] + emB[eboff + jj] + bbl[jj];
        ev = ev > 0.f ? ev : 0.01f * ev;
        init = act ? (ev + trl[TSTART * NT + jj]) : -1e30f;
    } else {
        size_t gi = eboff + (size_t)(tb0 - 1) * NT + jj;
        float ev = emA[gi] + emB[gi] + bbl[jj];
        ev = ev > 0.f ? ev : 0.01f * ev;
        init = act ? ev : -1e30f;
    }
    float aL = init, aV = init;

    float* bcL = (float*)bcL4[w];
    float* bcV = (float*)bcV4[w];

    float tcol[NT], Ecol[NT];
#pragma unroll
    for (int i = 0; i < NT; ++i) {
        tcol[i] = trl[i * NT + jj];
        Ecol[i] = __expf(tcol[i]);
    }

    if (c > 0) {
        for (int t = tb0; t <= te0; ++t) STEP2(t, 0)
    }
    float WvL = bcast0(aL), WvV = bcast0(aV);
    for (int t = tb; t <= te; ++t) STEP2(t, 1)
    float EvL = bcast0(aL), EvV = bcast0(aV);

    if (lane == 0) {
        Warr[b * NC + c]        = WvL;
        Earr[b * NC + c]        = EvL;
        Warr[(SB + b) * NC + c] = WvV;
        Earr[(SB + b) * NC + c] = EvV;
    }

    if (c == cl) {
        float ffL = act ? (aL + trl[jj * NT + TSTOP]) : -1e30f;
        float M = wave_max_f(ffL);
        float ssum = wave_sum_f(__expf(ffL - M));
        if (lane == 0) lse_local[b] = M + __logf(ssum);

        float ffV = act ? (aV + trl[jj * NT + TSTOP]) : -1e30f;
        float bv = ffV; int bi = lane;
#pragma unroll
        for (int off = 32; off > 0; off >>= 1) {
            float ov = __shfl_xor(bv, off, 64);
            int   oi = __shfl_xor(bi, off, 64);
            if (ov > bv || (ov == bv && oi < bi)) { bv = ov; bi = oi; }
        }
        if (lane == 0) { score_local[b] = bv; ltag[b] = bi; }
    }
}

// ---------------- finalize: parallel backtrace + loss atomicAdd ----------------
extern "C" __global__ __launch_bounds__(1024) void k_final(
    const float* __restrict__ emA, const float* __restrict__ emB,
    const float* __restrict__ bias,
    const int* __restrict__ hidx,
    const int* __restrict__ tags, const float* __restrict__ trans,
    const float* __restrict__ Warr, const float* __restrict__ Earr,
    const float* __restrict__ lse_local,
    const float* __restrict__ score_local, const int* __restrict__ ltag,
    const unsigned char* __restrict__ bp,
    float* __restrict__ loss_out, float* __restrict__ path_out,
    float* __restrict__ score_out)
{
    __shared__ unsigned char bpl[SS * 64];
    __shared__ unsigned char cmap[SS][40];
    __shared__ unsigned char exitmap[NC][64];
    __shared__ float gred[16];
    __shared__ int   ent[NC];

    int tid  = threadIdx.x;
    int lane = tid & 63;
    int w    = tid >> 6;
    int b    = blockIdx.x;

    {
        const int4* src = (const int4*)(bp + (size_t)b * SS * 64);
        int4* dst = (int4*)bpl;
        for (int i = tid; i < SS * 4; i += 1024) dst[i] = src[i];
    }

    int xm = 0;
    const int* hb = hidx + b * SS;
#pragma unroll
    for (int k = 0; k < SS / 64; ++k) xm = max(xm, hb[lane + 64 * k]);
#pragma unroll
    for (int off = 32; off > 0; off >>= 1) xm = max(xm, __shfl_xor(xm, off, 64));
    int xlen = xm;
    int cl   = (xlen >= 1) ? ((xlen - 1) >> 4) : 0;

    float g = 0.f;
    const int* tg = tags + b * SS;
    if (tid < SS) {
        int t = tid;
        if (t < xlen) {
            int tt = tg[t];
            size_t gi = ((size_t)b * SS + t) * NT + tt;
            float ev = emA[gi] + emB[gi] + bias[tt];
            ev = ev > 0.f ? ev : 0.01f * ev;
            g += ev;
            if (t >= 1) g += trans[tg[t - 1] * NT + tt];
        }
    }
    g = wave_sum_f(g);
    if (lane == 0) gred[w] = g;

    float kf = 0.f, kv = 0.f;
    if (w == 8) {
        if (lane < cl) {
            kf = Earr[(0 * SB + b) * NC + lane] - Warr[(0 * SB + b) * NC + lane + 1];
            kv = Earr[(1 * SB + b) * NC + lane] - Warr[(1 * SB + b) * NC + lane + 1];
        }
        kf = wave_sum_f(kf);
        kv = wave_sum_f(kv);
    }

    __syncthreads();

    if (tid == 512) {
        float gold = 0.f;
#pragma unroll
        for (int i = 0; i < 8; ++i) gold += gred[i];
        int tg0 = tg[0];
        int lt  = (xlen >= 1) ? tg[xlen - 1] : tg0;
        gold += trans[TSTART * NT + tg0] + trans[lt * NT + TSTOP];
        atomicAdd(loss_out, (lse_local[b] + kf) - gold);
        score_out[b] = score_local[b] + kv;
    }

    for (int cc = 0; cc < 2; ++cc) {
        int c = w * 2 + cc;
        if (xlen >= 1 && c <= cl) {
            int tb = (c == 0) ? 1 : c * CL;
            int te = c * CL + CL - 1; if (te > xlen - 1) te = xlen - 1;
            int m = lane;
            if (lane < NT) cmap[te][lane] = (unsigned char)m;
            for (int t = te; t >= tb; --t) {
                m = bpl[t * 64 + m];
                if (lane < NT) {
                    if (t > tb || c == 0) cmap[t - 1][lane] = (unsigned char)m;
                    else                  exitmap[c][lane]  = (unsigned char)m;
                }
            }
        }
    }
    __syncthreads();

    if (tid == 0 && xlen >= 1) {
        int e = ltag[b];
        for (int c2 = cl; c2 >= 0; --c2) {
            ent[c2] = e;
            if (c2 > 0) e = exitmap[c2][e];
        }
    }
    __syncthreads();

    if (tid < SS) {
        int t = tid;
        float* op = path_out + (size_t)b * SS;
        if (t >= xlen) op[t] = 0.f;
        else           op[t] = (float)cmap[t][ent[t >> 4]];
    }
}

extern "C" void kernel_launch(void* const* d_in, const int* in_sizes, int n_in,
                              void* d_out, int out_size, void* d_ws, size_t ws_size,
                              hipStream_t stream)
{
    const float* x1    = (const float*)d_in[0];
    const int*   hidx  = (const int*)d_in[1];
    const int*   tags  = (const int*)d_in[2];
    const float* W     = (const float*)d_in[3];
    const float* bias  = (const float*)d_in[4];
    const float* trans = (const float*)d_in[5];
    float* out = (float*)d_out;

    float* emitA       = (float*)d_ws;
    float* emitB       = emitA + (size_t)SB * SS * NT;
    float* Warr        = emitB + (size_t)SB * SS * NT;
    float* Earr        = Warr + 2 * SB * NC;
    float* lse_local   = Earr + 2 * SB * NC;
    float* score_local = lse_local + SB;
    int*   ltag        = (int*)(score_local + SB);
    float* spacer      = (float*)(ltag + SB);
    unsigned char* bp  = (unsigned char*)(spacer + SB);

    hipLaunchKernelGGL(k_emit, dim3(SB * SS / 64 * 2), dim3(512), 0, stream,
                       x1, hidx, W, bias, emitA, emitB);
    hipLaunchKernelGGL(k_scan, dim3(512), dim3(256), 0, stream,
                       emitA, emitB, bias, hidx, trans, Warr, Earr, lse_local,
                       score_local, ltag, bp);
    hipLaunchKernelGGL(k_final, dim3(SB), dim3(1024), 0, stream,
                       emitA, emitB, bias, hidx, tags, trans, Warr, Earr,
                       lse_local, score_local, ltag, bp,
                       out, out + 1, out + 1 + SB * SS);
}

// Round 16
// 200.950 us; speedup vs baseline: 1.4001x; 1.2939x over previous
//
#include <hip/hip_runtime.h>
#include <math.h>

#define SB 64
#define SS 512
#define SH 768
#define NT 36
#define TSTART 34
#define TSTOP 35
#define NC 32
#define CL 16

#define CFENCE() asm volatile("" ::: "memory")

__device__ __forceinline__ float wave_max_f(float v) {
#pragma unroll
    for (int off = 32; off > 0; off >>= 1) v = fmaxf(v, __shfl_xor(v, off, 64));
    return v;
}
__device__ __forceinline__ float wave_sum_f(float v) {
#pragma unroll
    for (int off = 32; off > 0; off >>= 1) v += __shfl_xor(v, off, 64);
    return v;
}
__device__ __forceinline__ float bcast0(float v) {
    return __uint_as_float(__builtin_amdgcn_readfirstlane(__float_as_uint(v)));
}

// ---------------- emissions (R1-structure; measured-best class ~67us) -------
// 8-way K-split (96 floats/wave), 64 rows/block, 512 thr/block, s_load W,
// depth-4 prefetch, red[8] slab reduce, staged float4 store.
// Emit variant ledger (R0-R15): depth-2/4/8, LDS-W @8/16w, vector-W,
// coalesced-LDS-X, K-split @32w(spill) — all non-broken variants 63-75us;
// no pipe saturated. This is the verified-best configuration (R10, 203us).
#define DOT4(pv, k4)                                                     \
    {                                                                    \
        const float* wr = Wq + (size_t)((k4) * 4) * NT;                  \
        _Pragma("unroll")                                                \
        for (int j = 0; j < NT; ++j) acc[j] += (pv).x * wr[j];           \
        _Pragma("unroll")                                                \
        for (int j = 0; j < NT; ++j) acc[j] += (pv).y * wr[NT + j];      \
        _Pragma("unroll")                                                \
        for (int j = 0; j < NT; ++j) acc[j] += (pv).z * wr[2 * NT + j];  \
        _Pragma("unroll")                                                \
        for (int j = 0; j < NT; ++j) acc[j] += (pv).w * wr[3 * NT + j];  \
    }

extern "C" __global__ __launch_bounds__(512) void k_emit(
    const float* __restrict__ x1, const int* __restrict__ hidx,
    const float* __restrict__ W, const float* __restrict__ bias,
    float* __restrict__ emit)
{
    __shared__ __align__(16) float red[8][64][37];

    int tid  = threadIdx.x;
    int lane = tid & 63;
    int q    = __builtin_amdgcn_readfirstlane(tid >> 6);   // 0..7 K-chunk
    int gr   = blockIdx.x * 64 + lane;
    int b    = gr >> 9;
    const float4* xr = (const float4*)(x1 + (size_t)(b * SS + hidx[gr]) * SH) + q * 24;
    const float*  Wq = W + (size_t)q * 96 * NT;

    float acc[NT];
#pragma unroll
    for (int j = 0; j < NT; ++j) acc[j] = 0.f;

    float4 p0 = xr[0], p1 = xr[1], p2 = xr[2], p3 = xr[3];
    for (int kb = 0; kb < 20; kb += 4) {
        float4 n0 = xr[kb + 4];
        float4 n1 = xr[kb + 5];
        float4 n2 = xr[kb + 6];
        float4 n3 = xr[kb + 7];
        DOT4(p0, kb);
        DOT4(p1, kb + 1);
        DOT4(p2, kb + 2);
        DOT4(p3, kb + 3);
        p0 = n0; p1 = n1; p2 = n2; p3 = n3;
    }
    DOT4(p0, 20);
    DOT4(p1, 21);
    DOT4(p2, 22);
    DOT4(p3, 23);

#pragma unroll
    for (int j = 0; j < NT; ++j) red[q][lane][j] = acc[j];
    __syncthreads();

    int r = tid >> 2, g = tid & 3;
    float vout[9];
    if (tid < 256) {
#pragma unroll
        for (int jj = 0; jj < 9; ++jj) {
            int j = g * 9 + jj;
            float v = bias[j];
#pragma unroll
            for (int qq = 0; qq < 8; ++qq) v += red[qq][r][j];
            vout[jj] = v > 0.f ? v : 0.01f * v;
        }
    }
    __syncthreads();
    if (tid < 256) {
        float* st = &red[0][0][0];
#pragma unroll
        for (int jj = 0; jj < 9; ++jj) st[r * NT + g * 9 + jj] = vout[jj];
    }
    __syncthreads();
    {
        const float4* st4 = (const float4*)&red[0][0][0];
        float4* op = (float4*)(emit + (size_t)blockIdx.x * 64 * NT);
        for (int i = tid; i < 576; i += 512) op[i] = st4[i];
    }
}

// ---------------- fused single-launch CRF scan (R10-verified) ----------------
// Each wave (kind,b,c) computes its OWN 8-step warmup over [cCL-8, cCL-1]
// (from emission guess at cCL-9), then runs its 16 real steps from that
// in-register vector. W_c (warmup end) and E_c (real end) lane-0 scalars
// go to global; k_final's correction kf = sum_{c=1..cl}(E_{c-1} - W_c) —
// identical telescope to the 2-pass delta. No cross-wave dependency.
#define LSE_STEP(T)                                                       \
    {                                                                     \
        float e_t = elsw[((T) - t0s) * NT + jj];                          \
        float m = bcast0(alpha);                                          \
        float p = __expf(alpha - m);                                      \
        bc[lane] = p;                                                     \
        CFENCE();                                                         \
        __builtin_amdgcn_wave_barrier();                                  \
        float s0 = 0.f, s1 = 0.f, s2 = 0.f, s3 = 0.f;                     \
        _Pragma("unroll")                                                 \
        for (int k = 0; k < 9; ++k) {                                     \
            float4 pv = bc4[w][k];                                        \
            s0 += pv.x * Ecol[4 * k];                                     \
            s1 += pv.y * Ecol[4 * k + 1];                                 \
            s2 += pv.z * Ecol[4 * k + 2];                                 \
            s3 += pv.w * Ecol[4 * k + 3];                                 \
        }                                                                 \
        CFENCE();                                                         \
        float anew = m + __logf((s0 + s1) + (s2 + s3)) + e_t;             \
        alpha = act ? anew : -1e30f;                                      \
    }

#define VIT_STEP(T, WRITEBP)                                              \
    {                                                                     \
        float e_t = elsw[((T) - t0s) * NT + jj];                          \
        bc[lane] = alpha;                                                 \
        CFENCE();                                                         \
        __builtin_amdgcn_wave_barrier();                                  \
        float b0 = -1e30f, b1 = -1e30f, b2 = -1e30f, b3 = -1e30f;         \
        int   i0 = 0, i1 = 1, i2 = 2, i3 = 3;                             \
        _Pragma("unroll")                                                 \
        for (int k = 0; k < 9; ++k) {                                     \
            float4 dv = bc4[w][k];                                        \
            float c0 = dv.x + tcol[4 * k];                                 \
            float c1 = dv.y + tcol[4 * k + 1];                             \
            float c2 = dv.z + tcol[4 * k + 2];                             \
            float c3 = dv.w + tcol[4 * k + 3];                             \
            if (c0 > b0) { b0 = c0; i0 = 4 * k; }                         \
            if (c1 > b1) { b1 = c1; i1 = 4 * k + 1; }                     \
            if (c2 > b2) { b2 = c2; i2 = 4 * k + 2; }                     \
            if (c3 > b3) { b3 = c3; i3 = 4 * k + 3; }                     \
        }                                                                 \
        CFENCE();                                                         \
        float best = b0; int bi = i0;                                     \
        if (b1 > best || (b1 == best && i1 < bi)) { best = b1; bi = i1; } \
        if (b2 > best || (b2 == best && i2 < bi)) { best = b2; bi = i2; } \
        if (b3 > best || (b3 == best && i3 < bi)) { best = b3; bi = i3; } \
        float dnew = best + e_t;                                          \
        alpha = act ? dnew : -1e30f;                                      \
        if ((WRITEBP) && act)                                             \
            bp[((size_t)b * SS + (T)) * 64 + jj] = (unsigned char)bi;     \
    }

extern "C" __global__ __launch_bounds__(256) void k_scan(
    const float* __restrict__ emit, const int* __restrict__ hidx,
    const float* __restrict__ trans,
    float* __restrict__ Warr, float* __restrict__ Earr,
    float* __restrict__ lse_local,
    float* __restrict__ score_local, int* __restrict__ ltag,
    unsigned char* __restrict__ bp)
{
    __shared__ float trl[NT * NT];
    __shared__ float els[4][1024];
    __shared__ float4 bc4[4][16];

    int tid  = threadIdx.x;
    int lane = tid & 63;
    int w    = __builtin_amdgcn_readfirstlane(tid >> 6);

    int wid  = blockIdx.x * 4 + w;
    int kind = wid >> 11;
    int rem  = wid & 2047;
    int b    = rem >> 5;
    int c    = rem & 31;

    const float* eb  = emit + (size_t)b * SS * NT;
    int t0s = (c > 0) ? (c * CL - 9) : 0;          // staged window start row
    const float* ebase = eb + (size_t)t0s * NT;    // row starts are 144B -> 16B aligned
    float* elsw = els[w];

#pragma unroll
    for (int i = 0; i < 4; ++i) {
        __builtin_amdgcn_global_load_lds(
            (const __attribute__((address_space(1))) void*)(ebase + i * 256 + lane * 4),
            (__attribute__((address_space(3))) void*)(elsw + i * 256), 16, 0, 0);
    }
    for (int i = tid; i < NT * NT; i += 256) trl[i] = trans[i];

    int  jj  = lane < NT ? lane : NT - 1;
    bool act = lane < NT;

    int xm = 0;
    const int* hb = hidx + b * SS;
#pragma unroll
    for (int k = 0; k < SS / 64; ++k) xm = max(xm, hb[lane + 64 * k]);
#pragma unroll
    for (int off = 32; off > 0; off >>= 1) xm = max(xm, __shfl_xor(xm, off, 64));
    int xlen = xm;
    int cl   = (xlen >= 1) ? ((xlen - 1) >> 4) : 0;

    // warmup range (chunk c-1's last 8 steps) and real range
    int tb0 = c * CL - 8;
    int te0 = c * CL; if (te0 > xlen) te0 = xlen; te0 -= 1;
    int tb  = c * CL; if (tb < 1) tb = 1;
    int te  = (c + 1) * CL; if (te > xlen) te = xlen; te -= 1;

    int didx = (kind * SB + b) * NC + c;

    float alpha;
    if (c == 0) alpha = act ? (eb[jj] + trans[TSTART * NT + jj]) : -1e30f;
    else        alpha = act ? eb[(size_t)(tb0 - 1) * NT + jj] : -1e30f;   // guess

    __syncthreads();

    float* bc = (float*)bc4[w];

    if (kind == 0) {
        float Ecol[NT];
#pragma unroll
        for (int i = 0; i < NT; ++i) Ecol[i] = __expf(trl[i * NT + jj]);
        if (c > 0) {
            for (int t = tb0; t <= te0; ++t) LSE_STEP(t)
        }
        float Wv = bcast0(alpha);
        for (int t = tb; t <= te; ++t) LSE_STEP(t)
        float Ev = bcast0(alpha);
        if (lane == 0) { Warr[didx] = Wv; Earr[didx] = Ev; }
        if (c == cl) {
            float ff = act ? (alpha + trl[jj * NT + TSTOP]) : -1e30f;
            float M = wave_max_f(ff);
            float ssum = wave_sum_f(__expf(ff - M));
            if (lane == 0) lse_local[b] = M + __logf(ssum);
        }
    } else {
        float tcol[NT];
#pragma unroll
        for (int i = 0; i < NT; ++i) tcol[i] = trl[i * NT + jj];
        if (c > 0) {
            for (int t = tb0; t <= te0; ++t) VIT_STEP(t, 0)
        }
        float Wv = bcast0(alpha);
        for (int t = tb; t <= te; ++t) VIT_STEP(t, 1)
        float Ev = bcast0(alpha);
        if (lane == 0) { Warr[didx] = Wv; Earr[didx] = Ev; }
        if (c == cl) {
            float ff = act ? (alpha + trl[jj * NT + TSTOP]) : -1e30f;
            float bv = ff; int bi = lane;
#pragma unroll
            for (int off = 32; off > 0; off >>= 1) {
                float ov = __shfl_xor(bv, off, 64);
                int   oi = __shfl_xor(bi, off, 64);
                if (ov > bv || (ov == bv && oi < bi)) { bv = ov; bi = oi; }
            }
            if (lane == 0) { score_local[b] = bv; ltag[b] = bi; }
        }
    }
}

// ---------------- finalize: parallel backtrace + loss atomicAdd ----------------
extern "C" __global__ __launch_bounds__(1024) void k_final(
    const float* __restrict__ emit, const int* __restrict__ hidx,
    const int* __restrict__ tags, const float* __restrict__ trans,
    const float* __restrict__ Warr, const float* __restrict__ Earr,
    const float* __restrict__ lse_local,
    const float* __restrict__ score_local, const int* __restrict__ ltag,
    const unsigned char* __restrict__ bp,
    float* __restrict__ loss_out, float* __restrict__ path_out,
    float* __restrict__ score_out)
{
    __shared__ unsigned char bpl[SS * 64];        // 32 KB: bp rows
    __shared__ unsigned char cmap[SS][40];        // 20 KB: composed maps, stride 40
    __shared__ unsigned char exitmap[NC][64];     // chunk-exit maps
    __shared__ float gred[16];
    __shared__ int   ent[NC];

    int tid  = threadIdx.x;
    int lane = tid & 63;
    int w    = tid >> 6;     // 0..15
    int b    = blockIdx.x;

    {
        const int4* src = (const int4*)(bp + (size_t)b * SS * 64);
        int4* dst = (int4*)bpl;
        for (int i = tid; i < SS * 4; i += 1024) dst[i] = src[i];
    }

    int xm = 0;
    const int* hb = hidx + b * SS;
#pragma unroll
    for (int k = 0; k < SS / 64; ++k) xm = max(xm, hb[lane + 64 * k]);
#pragma unroll
    for (int off = 32; off > 0; off >>= 1) xm = max(xm, __shfl_xor(xm, off, 64));
    int xlen = xm;
    int cl   = (xlen >= 1) ? ((xlen - 1) >> 4) : 0;

    // gold score: waves 0..7, one t per thread
    float g = 0.f;
    const int* tg = tags + b * SS;
    if (tid < SS) {
        int t = tid;
        if (t < xlen) {
            int tt = tg[t];
            g += emit[((size_t)b * SS + t) * NT + tt];
            if (t >= 1) g += trans[tg[t - 1] * NT + tt];
        }
    }
    g = wave_sum_f(g);
    if (lane == 0) gred[w] = g;

    // telescope correction: kf = sum_{c=1..cl}(E_{c-1} - W_c), lane-parallel
    float kf = 0.f, kv = 0.f;
    if (w == 8) {
        if (lane < cl) {
            kf = Earr[(0 * SB + b) * NC + lane] - Warr[(0 * SB + b) * NC + lane + 1];
            kv = Earr[(1 * SB + b) * NC + lane] - Warr[(1 * SB + b) * NC + lane + 1];
        }
        kf = wave_sum_f(kf);
        kv = wave_sum_f(kv);
    }

    __syncthreads();

    if (tid == 512) {
        float gold = 0.f;
#pragma unroll
        for (int i = 0; i < 8; ++i) gold += gred[i];
        int tg0 = tg[0];
        int lt  = (xlen >= 1) ? tg[xlen - 1] : tg0;
        gold += trans[TSTART * NT + tg0] + trans[lt * NT + TSTOP];
        atomicAdd(loss_out, (lse_local[b] + kf) - gold);
        score_out[b] = score_local[b] + kv;
    }

    // compose: wave w handles chunks 2w and 2w+1
    for (int cc = 0; cc < 2; ++cc) {
        int c = w * 2 + cc;
        if (xlen >= 1 && c <= cl) {
            int tb = (c == 0) ? 1 : c * CL;
            int te = c * CL + CL - 1; if (te > xlen - 1) te = xlen - 1;
            int m = lane;
            if (lane < NT) cmap[te][lane] = (unsigned char)m;
            for (int t = te; t >= tb; --t) {
                m = bpl[t * 64 + m];
                if (lane < NT) {
                    if (t > tb || c == 0) cmap[t - 1][lane] = (unsigned char)m;
                    else                  exitmap[c][lane]  = (unsigned char)m;
                }
            }
        }
    }
    __syncthreads();

    if (tid == 0 && xlen >= 1) {
        int e = ltag[b];
        for (int c2 = cl; c2 >= 0; --c2) {
            ent[c2] = e;
            if (c2 > 0) e = exitmap[c2][e];
        }
    }
    __syncthreads();

    if (tid < SS) {
        int t = tid;
        float* op = path_out + (size_t)b * SS;
        if (t >= xlen) op[t] = 0.f;
        else           op[t] = (float)cmap[t][ent[t >> 4]];
    }
}

extern "C" void kernel_launch(void* const* d_in, const int* in_sizes, int n_in,
                              void* d_out, int out_size, void* d_ws, size_t ws_size,
                              hipStream_t stream)
{
    const float* x1    = (const float*)d_in[0];
    const int*   hidx  = (const int*)d_in[1];
    const int*   tags  = (const int*)d_in[2];
    const float* W     = (const float*)d_in[3];
    const float* bias  = (const float*)d_in[4];
    const float* trans = (const float*)d_in[5];
    float* out = (float*)d_out;

    float* emit        = (float*)d_ws;
    float* Warr        = emit + (size_t)SB * SS * NT;        // 2*SB*NC floats
    float* Earr        = Warr + 2 * SB * NC;
    float* lse_local   = Earr + 2 * SB * NC;
    float* score_local = lse_local + SB;
    int*   ltag        = (int*)(score_local + SB);
    float* spacer      = (float*)(ltag + SB);
    unsigned char* bp  = (unsigned char*)(spacer + SB);

    hipLaunchKernelGGL(k_emit, dim3(SB * SS / 64), dim3(512), 0, stream,
                       x1, hidx, W, bias, emit);
    hipLaunchKernelGGL(k_scan, dim3(1024), dim3(256), 0, stream,
                       emit, hidx, trans, Warr, Earr, lse_local,
                       score_local, ltag, bp);
    hipLaunchKernelGGL(k_final, dim3(SB), dim3(1024), 0, stream,
                       emit, hidx, tags, trans, Warr, Earr, lse_local,
                       score_local, ltag, bp, out, out + 1, out + 1 + SB * SS);
}